// Round 1
// 839.981 us; speedup vs baseline: 1.0665x; 1.0665x over previous
//
#include <hip/hip_runtime.h>

#define TT    32        // timesteps
#define KDIM  262144    // fan-in (C*RF*L)
#define NFEAT 512       // output features
#define NFB   8         // features per block  (64 f-tiles -> 2 blocks/CU at nkc=8)
#define FPT   4         // features per thread
#define TPT   8         // timesteps per thread
#define BK    256       // k elements staged per step

// async global->LDS, 16B per lane; LDS dest = wave-uniform row base + lane*16
__device__ __forceinline__ void async_ld16(const float* g, float* lds_row) {
    __builtin_amdgcn_global_load_lds(
        (const __attribute__((address_space(1))) unsigned int*)g,
        (__attribute__((address_space(3))) unsigned int*)lds_row, 16, 0, 0);
}

// ---------------------------------------------------------------------------
// Kernel 1: partial GEMM. grid = (64 f-tiles, nkc k-chunks), block = 512.
// 8 waves = 2 fgrps x 4 tgrps. Lanes run along k (lane*4 within BK=256).
// x double-buffered in LDS via global_load_lds (64 KB -> 2 blocks/CU).
// Weights stream global->VGPR with a one-step register double-buffer: loads
// for step i+1 are issued before step i's compute, so the vmcnt(0) drain the
// compiler emits before each s_barrier lands AFTER a full compute phase.
// acc[4][8] = 32 VGPRs; total ~90 VGPRs -> 4 waves/SIMD, 2 blocks resident.
// ---------------------------------------------------------------------------
__global__ __launch_bounds__(512, 4)
void gemm_partial(const float* __restrict__ x, const float* __restrict__ w,
                  float* __restrict__ partial, int KC) {
    __shared__ float xs[2][TT][BK];      // 2 x 32 KB

    const int tid  = threadIdx.x;
    const int lane = tid & 63;
    const int wave = tid >> 6;           // 0..7
    const int fgrp = wave & 1;           // 0..1
    const int tgrp = wave >> 1;          // 0..3
    const int ftile  = blockIdx.x;       // 0..63
    const int kchunk = blockIdx.y;       // 0..nkc-1
    const int f0 = ftile * NFB + fgrp * FPT;
    const int t0 = tgrp * TPT;
    const size_t kbase = (size_t)kchunk * (size_t)KC;

    float acc[FPT][TPT];
#pragma unroll
    for (int j = 0; j < FPT; ++j)
#pragma unroll
        for (int t = 0; t < TPT; ++t) acc[j][t] = 0.f;

    const float* wbase = w + (size_t)f0 * KDIM + kbase + (lane << 2);
    const float* xbase = x + kbase + (lane << 2);

    // prologue: stage x buffer 0 (rows wave*4 .. wave*4+3), prefetch step-0 weights
#pragma unroll
    for (int r = 0; r < 4; ++r) {
        const int t = wave * 4 + r;
        async_ld16(xbase + (size_t)t * KDIM, &xs[0][t][0]);
    }
    float4 wcur[FPT];
#pragma unroll
    for (int j = 0; j < FPT; ++j)
        wcur[j] = *(const float4*)(wbase + (size_t)j * KDIM);

    int cur = 0;
    for (int ks = 0; ks < KC; ks += BK) {
        __syncthreads();                 // xs[cur] ready; wcur loads drained

        const bool notlast = (ks + BK < KC);

        // stage next x buffer (no reader of xs[cur^1] is active past the barrier)
        if (notlast) {
#pragma unroll
            for (int r = 0; r < 4; ++r) {
                const int t = wave * 4 + r;
                async_ld16(xbase + (size_t)t * KDIM + (ks + BK), &xs[cur ^ 1][t][0]);
            }
        }

        // prefetch next-step weights into the second register buffer
        float4 wnxt[FPT];
        if (notlast) {
#pragma unroll
            for (int j = 0; j < FPT; ++j)
                wnxt[j] = *(const float4*)(wbase + (size_t)j * KDIM + (ks + BK));
        }

        // compute: 8 ds_read_b128 + 128 v_fmac per thread per step
#pragma unroll
        for (int t = 0; t < TPT; ++t) {
            const float4 xv = *(const float4*)(&xs[cur][t0 + t][lane << 2]);
#pragma unroll
            for (int j = 0; j < FPT; ++j) {
                acc[j][t] = fmaf(wcur[j].x, xv.x, acc[j][t]);
                acc[j][t] = fmaf(wcur[j].y, xv.y, acc[j][t]);
                acc[j][t] = fmaf(wcur[j].z, xv.z, acc[j][t]);
                acc[j][t] = fmaf(wcur[j].w, xv.w, acc[j][t]);
            }
        }

        if (notlast) {
#pragma unroll
            for (int j = 0; j < FPT; ++j) wcur[j] = wnxt[j];
        }
        cur ^= 1;
    }

    // butterfly reduce across the 64 k-lanes
#pragma unroll
    for (int j = 0; j < FPT; ++j) {
#pragma unroll
        for (int t = 0; t < TPT; ++t) {
            float v = acc[j][t];
            v += __shfl_xor(v, 32, 64);
            v += __shfl_xor(v, 16, 64);
            v += __shfl_xor(v,  8, 64);
            v += __shfl_xor(v,  4, 64);
            v += __shfl_xor(v,  2, 64);
            v += __shfl_xor(v,  1, 64);
            acc[j][t] = v;
        }
    }

    if (lane == 0) {
#pragma unroll
        for (int j = 0; j < FPT; ++j) {
            float* p = partial + ((size_t)kchunk * NFEAT + (f0 + j)) * TT + t0;
            *(float4*)(p)     = make_float4(acc[j][0], acc[j][1], acc[j][2], acc[j][3]);
            *(float4*)(p + 4) = make_float4(acc[j][4], acc[j][5], acc[j][6], acc[j][7]);
        }
    }
}

// ---------------------------------------------------------------------------
// Kernel 2a: deterministic reduction over k-chunks -> raw potentials [o][t]
// ---------------------------------------------------------------------------
__global__ __launch_bounds__(256)
void reduce_chunks(const float* __restrict__ partial, int nkc,
                   float* __restrict__ potraw) {
    const int id = blockIdx.x * 256 + threadIdx.x;   // 0..16383 = o*32+t
    float s = 0.f;
    for (int c = 0; c < nkc; ++c)
        s += partial[(size_t)c * (NFEAT * TT) + id];
    potraw[id] = s;
}

// ---------------------------------------------------------------------------
// Kernel 2b: threshold + spike logic + 8-winner k-WTA + binary output.
// Single block, 512 threads (one per feature). Exact fp32 replication of the
// reference epilogue, numpy-argmax first-index tie-break included.
// ---------------------------------------------------------------------------
__global__ __launch_bounds__(512)
void finalize(const float* __restrict__ potraw, float* __restrict__ out) {
    const int o = threadIdx.x;       // feature index

    float pot[TT];
#pragma unroll
    for (int t = 0; t < TT; ++t) {
        const float s = potraw[o * TT + t];
        pot[t] = (s < 0.2f) ? 0.f : s;     // zero strictly below threshold
    }

    int cnt = 0;
#pragma unroll
    for (int t = 0; t < TT; ++t) cnt += (pot[t] > 0.f) ? 1 : 0;

    int first = TT - cnt;                  // clip((T - count), 0, T-1)
    if (first > TT - 1) first = TT - 1;
    float value = 0.f;
#pragma unroll
    for (int t = 0; t < TT; ++t)
        if (t == first) value = pot[t];

    __shared__ float rv[NFEAT];
    __shared__ int   ri[NFEAT];
    __shared__ float tot[NFEAT];
    __shared__ int   sel[NFEAT];

    // ---- v = max(spikes * values) * T
    rv[o] = (cnt > 0) ? value : 0.f;
    __syncthreads();
    for (int s = 256; s > 0; s >>= 1) {
        if (o < s) rv[o] = fmaxf(rv[o], rv[o + s]);
        __syncthreads();
    }
    const float v = rv[0] * (float)TT;
    __syncthreads();

    // total[o] = count * value + count * v   (0 when no spikes)
    tot[o] = (float)cnt * (value + v);
    sel[o] = 0;
    __syncthreads();

    // ---- iterative k-WTA, 8 winners, first-index argmax ties
    for (int it = 0; it < 8; ++it) {
        rv[o] = tot[o]; ri[o] = o;
        __syncthreads();
        for (int s = 256; s > 0; s >>= 1) {
            if (o < s) {
                const float v2 = rv[o + s];
                const int   i2 = ri[o + s];
                if (v2 > rv[o] || (v2 == rv[o] && i2 < ri[o])) {
                    rv[o] = v2; ri[o] = i2;
                }
            }
            __syncthreads();
        }
        if (o == 0) {
            if (rv[0] != 0.f) sel[ri[0]] = 1;
            tot[ri[0]] = 0.f;
        }
        __syncthreads();
    }

    // ---- out[t, o] = binary spikes of selected features
#pragma unroll
    for (int t = 0; t < TT; ++t)
        out[t * NFEAT + o] = (sel[o] && pot[t] > 0.f) ? 1.f : 0.f;
}

// ---------------------------------------------------------------------------
extern "C" void kernel_launch(void* const* d_in, const int* in_sizes, int n_in,
                              void* d_out, int out_size, void* d_ws, size_t ws_size,
                              hipStream_t stream) {
    const float* x = (const float*)d_in[0];   // rec_field (32,1,64,4096)
    const float* w = (const float*)d_in[1];   // weight   (512,1,64,4096)
    float* out = (float*)d_out;               // (32,512,1,1) flat

    // partials [nkc][512][32] + potraw [512][32] in workspace
    int nkc = 32;
    while (nkc > 1 &&
           ((size_t)(nkc + 1) * NFEAT * TT * sizeof(float)) > ws_size)
        nkc >>= 1;
    const int KC = KDIM / nkc;

    float* partial = (float*)d_ws;
    float* potraw  = partial + (size_t)nkc * NFEAT * TT;

    gemm_partial<<<dim3(NFEAT / NFB, nkc), 512, 0, stream>>>(x, w, partial, KC);
    reduce_chunks<<<(NFEAT * TT) / 256, 256, 0, stream>>>(partial, nkc, potraw);
    finalize<<<1, NFEAT, 0, stream>>>(potraw, out);
}

// Round 2
// 818.590 us; speedup vs baseline: 1.0944x; 1.0261x over previous
//
#include <hip/hip_runtime.h>

#define TT    32        // timesteps
#define KDIM  262144    // fan-in (C*RF*L)
#define NFEAT 512       // output features
#define NFB   8         // features per block
#define FPT   4         // features per thread
#define TPT   8         // timesteps per thread
#define BK    256       // k elements staged per step

// async global->LDS, 16B per lane; LDS dest = wave-uniform row base + lane*16
__device__ __forceinline__ void async_ld16(const float* g, float* lds_row) {
    __builtin_amdgcn_global_load_lds(
        (const __attribute__((address_space(1))) unsigned int*)g,
        (__attribute__((address_space(3))) unsigned int*)lds_row, 16, 0, 0);
}

// ---------------------------------------------------------------------------
// Kernel 1: partial GEMM. grid = (64 f-tiles, nkc k-chunks), block = 512.
// 8 waves = 2 fgrps x 4 tgrps. Lanes run along k (lane*4 within BK=256).
// BOTH x and w staged via global_load_lds, double-buffered:
//   xs: 32 rows x 1 KB (4 issues/wave), ws: 8 feature rows x 1 KB (1/wave).
// No weight VGPR stream: no duplicated t-group loads (512 MB unique weight
// traffic instead of 2 GB issued), no mid-iteration register vmcnt drain.
// One __syncthreads per sub-step (proven race-free placement: stage-after-
// barrier, drain happens at the NEXT barrier, i.e. AFTER the compute window).
// LDS = 64 KB (xs) + 16 KB (ws) = 80 KB -> 2 blocks/CU (160 KB pool).
// ---------------------------------------------------------------------------
__global__ __launch_bounds__(512, 4)
void gemm_partial(const float* __restrict__ x, const float* __restrict__ w,
                  float* __restrict__ partial, int KC) {
    __shared__ float xs[2][TT][BK];      // 2 x 32 KB
    __shared__ float ws[2][NFB][BK];     // 2 x  8 KB

    const int tid  = threadIdx.x;
    const int lane = tid & 63;
    const int wave = tid >> 6;           // 0..7
    const int fgrp = wave & 1;           // 0..1
    const int tgrp = wave >> 1;          // 0..3
    const int ftile  = blockIdx.x;       // 0..63
    const int kchunk = blockIdx.y;       // 0..nkc-1
    const int fbase = ftile * NFB;
    const int f0 = fbase + fgrp * FPT;
    const int t0 = tgrp * TPT;
    const int xrow = wave * 4;
    const size_t kbase = (size_t)kchunk * (size_t)KC;

    float acc[FPT][TPT];
#pragma unroll
    for (int j = 0; j < FPT; ++j)
#pragma unroll
        for (int t = 0; t < TPT; ++t) acc[j][t] = 0.f;

    // per-thread global sources (advance by ks only; all else precomputed)
    const float* xsrc = x + kbase + (lane << 2);
    const float* wsrc = w + (size_t)(fbase + wave) * KDIM + kbase + (lane << 2);

    // prologue: stage buffer 0
#pragma unroll
    for (int r = 0; r < 4; ++r)
        async_ld16(xsrc + (size_t)(xrow + r) * KDIM, &xs[0][xrow + r][0]);
    async_ld16(wsrc, &ws[0][wave][0]);

#define COMPUTE_STEP(buf)                                                     \
    {                                                                         \
        float4 wv[FPT];                                                       \
        _Pragma("unroll")                                                     \
        for (int j = 0; j < FPT; ++j)                                         \
            wv[j] = *(const float4*)(&ws[buf][fgrp * FPT + j][lane << 2]);    \
        _Pragma("unroll")                                                     \
        for (int t = 0; t < TPT; ++t) {                                       \
            const float4 xv = *(const float4*)(&xs[buf][t0 + t][lane << 2]);  \
            _Pragma("unroll")                                                 \
            for (int j = 0; j < FPT; ++j) {                                   \
                acc[j][t] = fmaf(wv[j].x, xv.x, acc[j][t]);                   \
                acc[j][t] = fmaf(wv[j].y, xv.y, acc[j][t]);                   \
                acc[j][t] = fmaf(wv[j].z, xv.z, acc[j][t]);                   \
                acc[j][t] = fmaf(wv[j].w, xv.w, acc[j][t]);                   \
            }                                                                 \
        }                                                                     \
    }

    // KC is a multiple of 2*BK (KDIM/nkc with nkc<=32 pow2 -> >=8192)
    for (int ks = 0; ks < KC; ks += 2 * BK) {
        // ---- sub-step A: compute buf 0, stage buf 1 (ks+BK < KC always)
        __syncthreads();                 // drains stage(buf0) after prior compute
#pragma unroll
        for (int r = 0; r < 4; ++r)
            async_ld16(xsrc + (size_t)(xrow + r) * KDIM + (ks + BK),
                       &xs[1][xrow + r][0]);
        async_ld16(wsrc + (ks + BK), &ws[1][wave][0]);
        COMPUTE_STEP(0)

        // ---- sub-step B: compute buf 1, stage buf 0 for next iter
        __syncthreads();
        if (ks + 2 * BK < KC) {
#pragma unroll
            for (int r = 0; r < 4; ++r)
                async_ld16(xsrc + (size_t)(xrow + r) * KDIM + (ks + 2 * BK),
                           &xs[0][xrow + r][0]);
            async_ld16(wsrc + (ks + 2 * BK), &ws[0][wave][0]);
        }
        COMPUTE_STEP(1)
    }
#undef COMPUTE_STEP

    // butterfly reduce across the 64 k-lanes
#pragma unroll
    for (int j = 0; j < FPT; ++j) {
#pragma unroll
        for (int t = 0; t < TPT; ++t) {
            float v = acc[j][t];
            v += __shfl_xor(v, 32, 64);
            v += __shfl_xor(v, 16, 64);
            v += __shfl_xor(v,  8, 64);
            v += __shfl_xor(v,  4, 64);
            v += __shfl_xor(v,  2, 64);
            v += __shfl_xor(v,  1, 64);
            acc[j][t] = v;
        }
    }

    if (lane == 0) {
#pragma unroll
        for (int j = 0; j < FPT; ++j) {
            float* p = partial + ((size_t)kchunk * NFEAT + (f0 + j)) * TT + t0;
            *(float4*)(p)     = make_float4(acc[j][0], acc[j][1], acc[j][2], acc[j][3]);
            *(float4*)(p + 4) = make_float4(acc[j][4], acc[j][5], acc[j][6], acc[j][7]);
        }
    }
}

// ---------------------------------------------------------------------------
// Kernel 2a: deterministic reduction over k-chunks -> raw potentials [o][t]
// ---------------------------------------------------------------------------
__global__ __launch_bounds__(256)
void reduce_chunks(const float* __restrict__ partial, int nkc,
                   float* __restrict__ potraw) {
    const int id = blockIdx.x * 256 + threadIdx.x;   // 0..16383 = o*32+t
    float s = 0.f;
    for (int c = 0; c < nkc; ++c)
        s += partial[(size_t)c * (NFEAT * TT) + id];
    potraw[id] = s;
}

// ---------------------------------------------------------------------------
// Kernel 2b: threshold + spike logic + 8-winner k-WTA + binary output.
// Single block, 512 threads (one per feature). Exact fp32 replication of the
// reference epilogue, numpy-argmax first-index tie-break included.
// ---------------------------------------------------------------------------
__global__ __launch_bounds__(512)
void finalize(const float* __restrict__ potraw, float* __restrict__ out) {
    const int o = threadIdx.x;       // feature index

    float pot[TT];
#pragma unroll
    for (int t = 0; t < TT; ++t) {
        const float s = potraw[o * TT + t];
        pot[t] = (s < 0.2f) ? 0.f : s;     // zero strictly below threshold
    }

    int cnt = 0;
#pragma unroll
    for (int t = 0; t < TT; ++t) cnt += (pot[t] > 0.f) ? 1 : 0;

    int first = TT - cnt;                  // clip((T - count), 0, T-1)
    if (first > TT - 1) first = TT - 1;
    float value = 0.f;
#pragma unroll
    for (int t = 0; t < TT; ++t)
        if (t == first) value = pot[t];

    __shared__ float rv[NFEAT];
    __shared__ int   ri[NFEAT];
    __shared__ float tot[NFEAT];
    __shared__ int   sel[NFEAT];

    // ---- v = max(spikes * values) * T
    rv[o] = (cnt > 0) ? value : 0.f;
    __syncthreads();
    for (int s = 256; s > 0; s >>= 1) {
        if (o < s) rv[o] = fmaxf(rv[o], rv[o + s]);
        __syncthreads();
    }
    const float v = rv[0] * (float)TT;
    __syncthreads();

    // total[o] = count * value + count * v   (0 when no spikes)
    tot[o] = (float)cnt * (value + v);
    sel[o] = 0;
    __syncthreads();

    // ---- iterative k-WTA, 8 winners, first-index argmax ties
    for (int it = 0; it < 8; ++it) {
        rv[o] = tot[o]; ri[o] = o;
        __syncthreads();
        for (int s = 256; s > 0; s >>= 1) {
            if (o < s) {
                const float v2 = rv[o + s];
                const int   i2 = ri[o + s];
                if (v2 > rv[o] || (v2 == rv[o] && i2 < ri[o])) {
                    rv[o] = v2; ri[o] = i2;
                }
            }
            __syncthreads();
        }
        if (o == 0) {
            if (rv[0] != 0.f) sel[ri[0]] = 1;
            tot[ri[0]] = 0.f;
        }
        __syncthreads();
    }

    // ---- out[t, o] = binary spikes of selected features
#pragma unroll
    for (int t = 0; t < TT; ++t)
        out[t * NFEAT + o] = (sel[o] && pot[t] > 0.f) ? 1.f : 0.f;
}

// ---------------------------------------------------------------------------
extern "C" void kernel_launch(void* const* d_in, const int* in_sizes, int n_in,
                              void* d_out, int out_size, void* d_ws, size_t ws_size,
                              hipStream_t stream) {
    const float* x = (const float*)d_in[0];   // rec_field (32,1,64,4096)
    const float* w = (const float*)d_in[1];   // weight   (512,1,64,4096)
    float* out = (float*)d_out;               // (32,512,1,1) flat

    // partials [nkc][512][32] + potraw [512][32] in workspace
    int nkc = 32;
    while (nkc > 1 &&
           ((size_t)(nkc + 1) * NFEAT * TT * sizeof(float)) > ws_size)
        nkc >>= 1;
    const int KC = KDIM / nkc;

    float* partial = (float*)d_ws;
    float* potraw  = partial + (size_t)nkc * NFEAT * TT;

    gemm_partial<<<dim3(NFEAT / NFB, nkc), 512, 0, stream>>>(x, w, partial, KC);
    reduce_chunks<<<(NFEAT * TT) / 256, 256, 0, stream>>>(partial, nkc, potraw);
    finalize<<<1, NFEAT, 0, stream>>>(potraw, out);
}